// Round 2
// baseline (1244.966 us; speedup 1.0000x reference)
//
#include <hip/hip_runtime.h>
#include <hip/hip_bf16.h>

#define N_NODES 50000
#define N_EDGES 800000
#define NODE_DIM 128
#define EDGE_DIM 128

// ---------------- kernels ----------------

// One thread per edge: in-degree histogram.
__global__ void deg_kernel(const int* __restrict__ edge_dst, int* __restrict__ deg) {
    int e = blockIdx.x * blockDim.x + threadIdx.x;
    if (e >= N_EDGES) return;
    atomicAdd(&deg[edge_dst[e]], 1);
}

// One wave (64 lanes) per edge: scatter-add 128 floats into accum[dst].
__global__ void accum_kernel(const float* __restrict__ e_lbl,
                             const int* __restrict__ edge_dst,
                             float* __restrict__ accum) {
    int gid  = blockIdx.x * blockDim.x + threadIdx.x;
    int wave = gid >> 6;
    int lane = gid & 63;
    if (wave >= N_EDGES) return;
    int dst = edge_dst[wave];
    const float2* src = reinterpret_cast<const float2*>(e_lbl + (size_t)wave * EDGE_DIM);
    float2 v = src[lane];
    float* dp = accum + (size_t)dst * EDGE_DIM + lane * 2;
    atomicAdd(dp + 0, v.x);
    atomicAdd(dp + 1, v.y);
}

// One thread per node: counts[deg[n]]++  (bucket sizes).
__global__ void counts_kernel(const int* __restrict__ deg, int* __restrict__ counts) {
    int n = blockIdx.x * blockDim.x + threadIdx.x;
    if (n >= N_NODES) return;
    atomicAdd(&counts[deg[n]], 1);
}

// One thread per 4 output floats over [N_NODES, 256].
__global__ void finalize_kernel(const float* __restrict__ h,
                                const float* __restrict__ accum,
                                const int* __restrict__ deg,
                                const int* __restrict__ counts,
                                float* __restrict__ out) {
    int idx = blockIdx.x * blockDim.x + threadIdx.x;   // 0 .. N_NODES*64
    if (idx >= N_NODES * 64) return;
    int n = idx >> 6;
    int q = idx & 63;        // which float4 within the 256-wide row
    int c0 = q * 4;

    int d = deg[n];
    float4 o;
    if (d == 0) {
        o = make_float4(0.f, 0.f, 0.f, 0.f);
    } else {
        float4 x;
        if (c0 < NODE_DIM) {
            x = *reinterpret_cast<const float4*>(h + (size_t)n * NODE_DIM + c0);
        } else {
            x = *reinterpret_cast<const float4*>(accum + (size_t)n * EDGE_DIM + (c0 - NODE_DIM));
            float inv = 1.0f / (float)counts[d];
            x.x *= inv; x.y *= inv; x.z *= inv; x.w *= inv;
        }
        o.x = x.x > 0.f ? x.x : expm1f(x.x);
        o.y = x.y > 0.f ? x.y : expm1f(x.y);
        o.z = x.z > 0.f ? x.z : expm1f(x.z);
        o.w = x.w > 0.f ? x.w : expm1f(x.w);
    }
    *reinterpret_cast<float4*>(out + (size_t)n * 256 + c0) = o;
}

// ---------------- launch ----------------

extern "C" void kernel_launch(void* const* d_in, const int* in_sizes, int n_in,
                              void* d_out, int out_size, void* d_ws, size_t ws_size,
                              hipStream_t stream) {
    const float* h       = (const float*)d_in[0];
    const float* e_lbl   = (const float*)d_in[1];
    const int*   edge_dst= (const int*)d_in[2];
    float* out = (float*)d_out;

    // ws layout: accum [N*128 f32] | deg [N i32] | counts [N_EDGES+1 i32]
    char* ws = (char*)d_ws;
    float* accum  = (float*)ws;
    size_t accum_bytes = (size_t)N_NODES * EDGE_DIM * sizeof(float);   // 25.6 MB
    int* deg      = (int*)(ws + accum_bytes);
    size_t deg_bytes = (size_t)N_NODES * sizeof(int);                  // 200 KB
    int* counts   = (int*)(ws + accum_bytes + deg_bytes);
    size_t counts_bytes = (size_t)(N_EDGES + 1) * sizeof(int);         // 3.2 MB

    hipMemsetAsync(d_ws, 0, accum_bytes + deg_bytes + counts_bytes, stream);

    deg_kernel<<<(N_EDGES + 255) / 256, 256, 0, stream>>>(edge_dst, deg);

    // one wave per edge -> N_EDGES*64 threads
    accum_kernel<<<(N_EDGES * 64) / 256, 256, 0, stream>>>(e_lbl, edge_dst, accum);

    counts_kernel<<<(N_NODES + 255) / 256, 256, 0, stream>>>(deg, counts);

    finalize_kernel<<<(N_NODES * 64 + 255) / 256, 256, 0, stream>>>(h, accum, deg, counts, out);
}